// Round 5
// baseline (499.872 us; speedup 1.0000x reference)
//
#include <hip/hip_runtime.h>
#include <hip/hip_bf16.h>
#include <stdint.h>

// B=4, M=256, N=64, D=512, C=1024
// out[b,m,n,c] = log_softmax_c( tanh(pe[b,m,:] + pd[b,n,:]) . W2[c,:] + b2[c] )
// pe = enc @ W1[:, :D]^T ; pd = dec @ W1[:, D:]^T + b1

typedef __bf16         bf16x8 __attribute__((ext_vector_type(8)));
typedef float          f32x4  __attribute__((ext_vector_type(4)));
typedef unsigned short u16x8  __attribute__((ext_vector_type(8)));

__device__ __forceinline__ unsigned short f2bf(float f) {
  unsigned int u = __float_as_uint(f);
  u += 0x7fffu + ((u >> 16) & 1u);          // RNE
  return (unsigned short)(u >> 16);
}

__device__ __forceinline__ f32x4 mfma16(u16x8 a, u16x8 b, f32x4 c) {
  return __builtin_amdgcn_mfma_f32_16x16x32_bf16(
      __builtin_bit_cast(bf16x8, a), __builtin_bit_cast(bf16x8, b), c, 0, 0, 0);
}

// ---------------- prep: f32 -> bf16 conversions + cnt zeroing ----------------
__global__ __launch_bounds__(256) void prep_kernel(
    const float* __restrict__ enc, const float* __restrict__ dec,
    const float* __restrict__ W1,  const float* __restrict__ W2,
    unsigned short* __restrict__ encB, unsigned short* __restrict__ decB,
    unsigned short* __restrict__ W1eB, unsigned short* __restrict__ W1dB,
    unsigned short* __restrict__ W2B,  unsigned int* __restrict__ cnt)
{
  const int i = blockIdx.x * 256 + threadIdx.x;   // 0 .. 524287
  encB[i] = f2bf(enc[i]);
  W2B[i]  = f2bf(W2[i]);
  if (i < 262144) {                                // W1 is [512][1024]
    const int k = i >> 9, d = i & 511;
    W1eB[i] = f2bf(W1[k * 1024 + d]);
    W1dB[i] = f2bf(W1[k * 1024 + 512 + d]);
  }
  if (i < 131072) decB[i] = f2bf(dec[i]);
  if (i < 1024)   cnt[i] = 0;                      // pair-merge flags (reset每 launch)
}

// ---------------- proj: out[r][c] = sum_d A[r][d]*Wt[c][d] (+bias[c]) ----------------
__global__ __launch_bounds__(256) void proj_kernel(
    const unsigned short* __restrict__ A, const unsigned short* __restrict__ Wt,
    const float* __restrict__ bias, float* __restrict__ out)
{
  const int rtile = blockIdx.x >> 3;
  const int ctile = blockIdx.x & 7;
  const int w = threadIdx.x >> 6;
  const int l = threadIdx.x & 63;
  const int q = l >> 4, ln = l & 15;

  f32x4 acc[4] = {};
  const unsigned short* Ab = A  + (size_t)(rtile * 64 + ln) * 512 + q * 8;
  const unsigned short* Wb = Wt + (size_t)(ctile * 64 + w * 16 + ln) * 512 + q * 8;

#pragma unroll 4
  for (int ks = 0; ks < 16; ++ks) {
    u16x8 bv = *(const u16x8*)(Wb + ks * 32);
#pragma unroll
    for (int rf = 0; rf < 4; ++rf) {
      u16x8 av = *(const u16x8*)(Ab + rf * 16 * 512 + ks * 32);
      acc[rf] = mfma16(av, bv, acc[rf]);
    }
  }
  const int col = ctile * 64 + w * 16 + ln;
  const float bv = bias ? bias[col] : 0.0f;
#pragma unroll
  for (int rf = 0; rf < 4; ++rf)
#pragma unroll
    for (int j = 0; j < 4; ++j)
      out[(size_t)(rtile * 64 + rf * 16 + q * 4 + j) * 512 + col] = acc[rf][j] + bv;
}

// ---------------- joint: fused tanh-GEMM + bias + log_softmax ----------------
// grid = 2*B*M = 2048 blocks, block = 512 threads (8 waves).
// Pair p = blk>>1 = (b,m); side = blk&1 owns cols [side*512, side*512+512).
// Wave w: all 64 rows x cols side*512 + [w*64, w*64+64). acc 4x4 f32x4 = 64 f32.
// Pair exchanges per-row (max, sumexp) via ws (device-scope atomics).
__global__ __launch_bounds__(512, 4) void joint_kernel(
    const float* __restrict__ pe, const float* __restrict__ pd,
    const unsigned short* __restrict__ W2B, const float* __restrict__ b2,
    unsigned long long* __restrict__ part, unsigned int* __restrict__ cnt,
    float* __restrict__ out)
{
  __shared__ unsigned short A_sh[64 * 512];   // 64 KiB, XOR-swizzled bf16 tile
  __shared__ float2 red[64][8];               // per-row, per-wave (max, sumexp)
  __shared__ float  lse_sh[64];

  const int blk  = blockIdx.x;
  const int p    = blk >> 1;           // b*256 + m
  const int side = blk & 1;
  const int b    = p >> 8;
  const int tid  = threadIdx.x;
  const int w = tid >> 6, l = tid & 63;
  const int q = l >> 4, ln = l & 15;

  // ---- generate A[n][d] = tanh(pe[m,d] + pd[n,d]) into swizzled LDS ----
  // wave w owns rows w*8..w*8+7; lane l owns d = l*8..l*8+7 (coalesced)
  {
    const float* per = pe + (size_t)p * 512 + l * 8;
    const float4 pe0 = *(const float4*)(per);
    const float4 pe1 = *(const float4*)(per + 4);
#pragma unroll
    for (int r = 0; r < 8; ++r) {
      const int n = w * 8 + r;
      const float* pdr = pd + (size_t)(b * 64 + n) * 512 + l * 8;
      const float4 q0 = *(const float4*)(pdr);
      const float4 q1 = *(const float4*)(pdr + 4);
      float x[8] = {pe0.x + q0.x, pe0.y + q0.y, pe0.z + q0.z, pe0.w + q0.w,
                    pe1.x + q1.x, pe1.y + q1.y, pe1.z + q1.z, pe1.w + q1.w};
      u16x8 pk;
#pragma unroll
      for (int e = 0; e < 8; ++e) {
        const float ex = __expf(2.0f * x[e]);                   // tanh = 1 - 2/(e^2x+1)
        const float t  = 1.0f - 2.0f * __builtin_amdgcn_rcpf(ex + 1.0f);
        pk[e] = f2bf(t);
      }
      *(u16x8*)((char*)A_sh + n * 1024 + ((l ^ (n & 7)) << 4)) = pk;
    }
  }
  __syncthreads();

  // ---- GEMM: wave w owns cols side*512 + [w*64, w*64+64), rows 0..63 ----
  f32x4 acc[4][4];
#pragma unroll
  for (int rf = 0; rf < 4; ++rf)
#pragma unroll
    for (int cf = 0; cf < 4; ++cf) acc[rf][cf] = (f32x4){0.f, 0.f, 0.f, 0.f};

  const char* Abase = (const char*)A_sh + ln * 1024;   // + rf*16384, row = rf*16+ln
  const unsigned short* Wb = W2B + (size_t)(side * 512 + w * 64 + ln) * 512 + q * 8;
  const int xr = ln & 7;                                // row&7 == ln&7

  for (int ks = 0; ks < 16; ++ks) {
    u16x8 bv[4], av[4];
#pragma unroll
    for (int cf = 0; cf < 4; ++cf)
      bv[cf] = *(const u16x8*)(Wb + cf * 8192 + ks * 32);
#pragma unroll
    for (int rf = 0; rf < 4; ++rf)
      av[rf] = *(const u16x8*)(Abase + rf * 16384 + (((ks * 4 + q) ^ xr) << 4));
#pragma unroll
    for (int rf = 0; rf < 4; ++rf)
#pragma unroll
      for (int cf = 0; cf < 4; ++cf)
        acc[rf][cf] = mfma16(av[rf], bv[cf], acc[rf][cf]);
  }

  // ---- epilogue: + b2, per-wave partial (max,sumexp), pair merge, subtract ----
  float b2v[4];
#pragma unroll
  for (int cf = 0; cf < 4; ++cf) b2v[cf] = b2[side * 512 + w * 64 + cf * 16 + ln];
#pragma unroll
  for (int rf = 0; rf < 4; ++rf)
#pragma unroll
    for (int cf = 0; cf < 4; ++cf)
#pragma unroll
      for (int j = 0; j < 4; ++j) acc[rf][cf][j] += b2v[cf];

  {
    float mx[4][4], sm[4][4];
#pragma unroll
    for (int rf = 0; rf < 4; ++rf)
#pragma unroll
      for (int j = 0; j < 4; ++j) {
        float m = acc[rf][0][j];
#pragma unroll
        for (int cf = 1; cf < 4; ++cf) m = fmaxf(m, acc[rf][cf][j]);
        mx[rf][j] = m;
      }
#pragma unroll
    for (int o = 1; o < 16; o <<= 1)
#pragma unroll
      for (int rf = 0; rf < 4; ++rf)
#pragma unroll
        for (int j = 0; j < 4; ++j)
          mx[rf][j] = fmaxf(mx[rf][j], __shfl_xor(mx[rf][j], o));
#pragma unroll
    for (int rf = 0; rf < 4; ++rf)
#pragma unroll
      for (int j = 0; j < 4; ++j) {
        float s = 0.f;
#pragma unroll
        for (int cf = 0; cf < 4; ++cf) s += __expf(acc[rf][cf][j] - mx[rf][j]);
        sm[rf][j] = s;
      }
#pragma unroll
    for (int o = 1; o < 16; o <<= 1)
#pragma unroll
      for (int rf = 0; rf < 4; ++rf)
#pragma unroll
        for (int j = 0; j < 4; ++j)
          sm[rf][j] += __shfl_xor(sm[rf][j], o);
    if (ln == 0) {
#pragma unroll
      for (int rf = 0; rf < 4; ++rf)
#pragma unroll
        for (int j = 0; j < 4; ++j)
          red[rf * 16 + q * 4 + j][w] = make_float2(mx[rf][j], sm[rf][j]);
    }
  }
  __syncthreads();

  // block-local merge of 8 wave-partials (threads 0..63, one row each),
  // publish to partner, then merge partner's half.
  float Mf = 0.f, S = 0.f;
  if (tid < 64) {
    Mf = red[tid][0].x;
#pragma unroll
    for (int ww = 1; ww < 8; ++ww) Mf = fmaxf(Mf, red[tid][ww].x);
#pragma unroll
    for (int ww = 0; ww < 8; ++ww) S += red[tid][ww].y * __expf(red[tid][ww].x - Mf);
    const unsigned long long pk =
        ((unsigned long long)__float_as_uint(S) << 32) | __float_as_uint(Mf);
    __hip_atomic_store(&part[(size_t)((p << 1) | side) * 64 + tid], pk,
                       __ATOMIC_RELAXED, __HIP_MEMORY_SCOPE_AGENT);
  }
  __threadfence();
  if (tid == 0) {
    __hip_atomic_fetch_add(&cnt[p], 1u, __ATOMIC_RELEASE, __HIP_MEMORY_SCOPE_AGENT);
    while (__hip_atomic_load(&cnt[p], __ATOMIC_ACQUIRE, __HIP_MEMORY_SCOPE_AGENT) < 2u)
      __builtin_amdgcn_s_sleep(16);
  }
  __syncthreads();
  if (tid < 64) {
    const unsigned long long po =
        __hip_atomic_load(&part[(size_t)((p << 1) | (side ^ 1)) * 64 + tid],
                          __ATOMIC_RELAXED, __HIP_MEMORY_SCOPE_AGENT);
    const float Mo = __uint_as_float((unsigned int)po);
    const float So = __uint_as_float((unsigned int)(po >> 32));
    const float M2 = fmaxf(Mf, Mo);
    const float St = S * __expf(Mf - M2) + So * __expf(Mo - M2);
    lse_sh[tid] = M2 + __logf(St);
  }
  __syncthreads();

  // final: out = acc - lse
  float* outb = out + (size_t)p * (64 * 1024) + side * 512 + w * 64 + ln;
#pragma unroll
  for (int rf = 0; rf < 4; ++rf)
#pragma unroll
    for (int j = 0; j < 4; ++j) {
      const int row = rf * 16 + q * 4 + j;
      const float lse = lse_sh[row];
      float* orow = outb + (size_t)row * 1024;
#pragma unroll
      for (int cf = 0; cf < 4; ++cf) orow[cf * 16] = acc[rf][cf][j] - lse;
    }
}

extern "C" void kernel_launch(void* const* d_in, const int* in_sizes, int n_in,
                              void* d_out, int out_size, void* d_ws, size_t ws_size,
                              hipStream_t stream) {
  (void)in_sizes; (void)n_in; (void)out_size; (void)ws_size;
  const float* enc = (const float*)d_in[0];
  const float* dec = (const float*)d_in[1];
  const float* W1  = (const float*)d_in[2];
  const float* b1  = (const float*)d_in[3];
  const float* W2  = (const float*)d_in[4];
  const float* b2  = (const float*)d_in[5];
  float* out = (float*)d_out;

  char* ws = (char*)d_ws;
  unsigned short* encB = (unsigned short*)(ws + 0);        // 1 MiB   (524288 el)
  unsigned short* decB = (unsigned short*)(ws + 1048576);  // 256 KiB (131072 el)
  unsigned short* W1eB = (unsigned short*)(ws + 1310720);  // 512 KiB (262144 el)
  unsigned short* W1dB = (unsigned short*)(ws + 1835008);  // 512 KiB (262144 el)
  unsigned short* W2B  = (unsigned short*)(ws + 2359296);  // 1 MiB   (524288 el)
  float*          pe   = (float*)(ws + 3407872);           // 2 MiB  [1024][512]
  float*          pd   = (float*)(ws + 5505024);           // 512 KiB [256][512]
  unsigned long long* part = (unsigned long long*)(ws + 6029312);  // 1 MiB [1024][2][64]
  unsigned int*       cnt  = (unsigned int*)(ws + 7077888);        // 4 KiB [1024]

  prep_kernel<<<2048, 256, 0, stream>>>(enc, dec, W1, W2, encB, decB, W1eB, W1dB, W2B, cnt);
  proj_kernel<<<128, 256, 0, stream>>>(encB, W1eB, nullptr, pe);   // pe: 1024x512
  proj_kernel<<< 32, 256, 0, stream>>>(decB, W1dB, b1,      pd);   // pd:  256x512
  joint_kernel<<<2048, 512, 0, stream>>>(pe, pd, W2B, b2, part, cnt, out);
}

// Round 6
// 452.286 us; speedup vs baseline: 1.1052x; 1.1052x over previous
//
#include <hip/hip_runtime.h>
#include <hip/hip_bf16.h>
#include <stdint.h>

// B=4, M=256, N=64, D=512, C=1024
// out[b,m,n,c] = log_softmax_c( tanh(pe[b,m,:] + pd[b,n,:]) . W2[c,:] + b2[c] )
// pe = enc @ W1[:, :D]^T ; pd = dec @ W1[:, D:]^T + b1

typedef __bf16         bf16x8 __attribute__((ext_vector_type(8)));
typedef float          f32x4  __attribute__((ext_vector_type(4)));
typedef unsigned short u16x8  __attribute__((ext_vector_type(8)));

__device__ __forceinline__ unsigned short f2bf(float f) {
  unsigned int u = __float_as_uint(f);
  u += 0x7fffu + ((u >> 16) & 1u);          // RNE
  return (unsigned short)(u >> 16);
}

__device__ __forceinline__ f32x4 mfma16(u16x8 a, u16x8 b, f32x4 c) {
  return __builtin_amdgcn_mfma_f32_16x16x32_bf16(
      __builtin_bit_cast(bf16x8, a), __builtin_bit_cast(bf16x8, b), c, 0, 0, 0);
}

// barrier that does NOT drain vmem (stores/loads stay in flight); LDS-safe.
#define LGKM_BAR() do {                                   \
  asm volatile("s_waitcnt lgkmcnt(0)" ::: "memory");      \
  __builtin_amdgcn_s_barrier();                           \
  __builtin_amdgcn_sched_barrier(0);                      \
} while (0)

// ---------------- prep: f32 -> bf16 conversions ----------------
__global__ __launch_bounds__(256) void prep_kernel(
    const float* __restrict__ enc, const float* __restrict__ dec,
    const float* __restrict__ W1,  const float* __restrict__ W2,
    unsigned short* __restrict__ encB, unsigned short* __restrict__ decB,
    unsigned short* __restrict__ W1eB, unsigned short* __restrict__ W1dB,
    unsigned short* __restrict__ W2B)
{
  const int i = blockIdx.x * 256 + threadIdx.x;   // 0 .. 524287
  encB[i] = f2bf(enc[i]);
  W2B[i]  = f2bf(W2[i]);
  if (i < 262144) {                                // W1 is [512][1024]
    const int k = i >> 9, d = i & 511;
    W1eB[i] = f2bf(W1[k * 1024 + d]);
    W1dB[i] = f2bf(W1[k * 1024 + 512 + d]);
  }
  if (i < 131072) decB[i] = f2bf(dec[i]);
}

// ---------------- proj: out[r][c] = sum_d A[r][d]*Wt[c][d] (+bias[c]) ----------------
__global__ __launch_bounds__(256) void proj_kernel(
    const unsigned short* __restrict__ A, const unsigned short* __restrict__ Wt,
    const float* __restrict__ bias, float* __restrict__ out)
{
  const int rtile = blockIdx.x >> 3;
  const int ctile = blockIdx.x & 7;
  const int w = threadIdx.x >> 6;
  const int l = threadIdx.x & 63;
  const int q = l >> 4, ln = l & 15;

  f32x4 acc[4] = {};
  const unsigned short* Ab = A  + (size_t)(rtile * 64 + ln) * 512 + q * 8;
  const unsigned short* Wb = Wt + (size_t)(ctile * 64 + w * 16 + ln) * 512 + q * 8;

#pragma unroll 4
  for (int ks = 0; ks < 16; ++ks) {
    u16x8 bv = *(const u16x8*)(Wb + ks * 32);
#pragma unroll
    for (int rf = 0; rf < 4; ++rf) {
      u16x8 av = *(const u16x8*)(Ab + rf * 16 * 512 + ks * 32);
      acc[rf] = mfma16(av, bv, acc[rf]);
    }
  }
  const int col = ctile * 64 + w * 16 + ln;
  const float bv = bias ? bias[col] : 0.0f;
#pragma unroll
  for (int rf = 0; rf < 4; ++rf)
#pragma unroll
    for (int j = 0; j < 4; ++j)
      out[(size_t)(rtile * 64 + rf * 16 + q * 4 + j) * 512 + col] = acc[rf][j] + bv;
}

// ---------------- joint: persistent fused tanh-GEMM + bias + log_softmax ----------------
// grid = 256 blocks (1/CU), block = 1024 threads (16 waves).
// Block blk: b = blk>>6, m = (blk&63)*4 + t for t = 0..3 (4 tiles, pipelined).
// Per tile: wave w owns all 64 rows x cols [w*64, w*64+64). acc 4x4 f32x4 = 64 f32.
// A double-buffered in LDS; gen(t+1) overlaps GEMM/store-drain of tile t.
__global__ __launch_bounds__(1024, 4) void joint_kernel(
    const float* __restrict__ pe, const float* __restrict__ pd,
    const unsigned short* __restrict__ W2B, const float* __restrict__ b2,
    float* __restrict__ out)
{
  __shared__ unsigned short A_sh[2][64 * 512];   // 2 x 64 KiB, XOR-swizzled
  __shared__ float2 red[64][17];                 // padded: no bank conflicts
  __shared__ float  lse_sh[64];

  const int blk = blockIdx.x;            // 0..255
  const int b   = blk >> 6;
  const int m0  = (blk & 63) << 2;
  const int tid = threadIdx.x;
  const int w = tid >> 6, l = tid & 63;
  const int q = l >> 4, ln = l & 15;

  const unsigned short* Wb = W2B + (size_t)(w * 64 + ln) * 512 + q * 8;  // + cf*8192 + ks*32
  float b2v[4];
#pragma unroll
  for (int cf = 0; cf < 4; ++cf) b2v[cf] = b2[w * 64 + cf * 16 + ln];

  // gen: A[n][d] = tanh(pe[m,d] + pd[n,d]) for tile tt into A_sh[bufsel].
  // wave w owns rows w*4..w*4+3; lane l owns d = l*8..l*8+7 (coalesced).
  auto gen = [&](int tt, int bufsel) {
    const int p = (b << 8) | (m0 + tt);
    const float* per = pe + (size_t)p * 512 + l * 8;
    const float4 pe0 = *(const float4*)(per);
    const float4 pe1 = *(const float4*)(per + 4);
    char* base = (char*)(A_sh[bufsel]);
#pragma unroll
    for (int r = 0; r < 4; ++r) {
      const int n = (w << 2) | r;
      const float* pdr = pd + (size_t)((b << 6) | n) * 512 + l * 8;
      const float4 q0 = *(const float4*)(pdr);
      const float4 q1 = *(const float4*)(pdr + 4);
      float x[8] = {pe0.x + q0.x, pe0.y + q0.y, pe0.z + q0.z, pe0.w + q0.w,
                    pe1.x + q1.x, pe1.y + q1.y, pe1.z + q1.z, pe1.w + q1.w};
      u16x8 pk;
#pragma unroll
      for (int e = 0; e < 8; ++e) {
        const float ex = __expf(2.0f * x[e]);                    // tanh = 1 - 2/(e^2x+1)
        const float tv = 1.0f - 2.0f * __builtin_amdgcn_rcpf(ex + 1.0f);
        pk[e] = f2bf(tv);
      }
      *(u16x8*)(base + n * 1024 + ((l ^ (n & 7)) << 4)) = pk;
    }
  };

  gen(0, 0);
  LGKM_BAR();

  for (int t = 0; t < 4; ++t) {
    const int cur = t & 1;
    if (t < 3) gen(t + 1, cur ^ 1);    // fill idle buffer (visible after next bar)

    // ---- GEMM tile t from A_sh[cur] ----
    f32x4 acc[4][4];
#pragma unroll
    for (int rf = 0; rf < 4; ++rf)
#pragma unroll
      for (int cf = 0; cf < 4; ++cf) acc[rf][cf] = (f32x4){0.f, 0.f, 0.f, 0.f};

    const char* Abase = (const char*)(A_sh[cur]) + ln * 1024;  // + rf*16384
    const int xr = ln & 7;

    for (int ks = 0; ks < 16; ++ks) {
      u16x8 bv[4], av[4];
#pragma unroll
      for (int cf = 0; cf < 4; ++cf)
        bv[cf] = *(const u16x8*)(Wb + cf * 8192 + ks * 32);
#pragma unroll
      for (int rf = 0; rf < 4; ++rf)
        av[rf] = *(const u16x8*)(Abase + rf * 16384 + (((ks * 4 + q) ^ xr) << 4));
#pragma unroll
      for (int rf = 0; rf < 4; ++rf)
#pragma unroll
        for (int cf = 0; cf < 4; ++cf)
          acc[rf][cf] = mfma16(av[rf], bv[cf], acc[rf][cf]);
    }
    LGKM_BAR();   // A(t+1) complete; A_sh[cur] reads done; stores stay in flight

    // ---- epilogue: + b2, log_softmax over 1024 cols per row ----
#pragma unroll
    for (int rf = 0; rf < 4; ++rf)
#pragma unroll
      for (int cf = 0; cf < 4; ++cf)
#pragma unroll
        for (int j = 0; j < 4; ++j) acc[rf][cf][j] += b2v[cf];

    {
      float mx[4][4], sm[4][4];
#pragma unroll
      for (int rf = 0; rf < 4; ++rf)
#pragma unroll
        for (int j = 0; j < 4; ++j) {
          float m = acc[rf][0][j];
#pragma unroll
          for (int cf = 1; cf < 4; ++cf) m = fmaxf(m, acc[rf][cf][j]);
          mx[rf][j] = m;
        }
#pragma unroll
      for (int o = 1; o < 16; o <<= 1)
#pragma unroll
        for (int rf = 0; rf < 4; ++rf)
#pragma unroll
          for (int j = 0; j < 4; ++j)
            mx[rf][j] = fmaxf(mx[rf][j], __shfl_xor(mx[rf][j], o));
#pragma unroll
      for (int rf = 0; rf < 4; ++rf)
#pragma unroll
        for (int j = 0; j < 4; ++j) {
          float s = 0.f;
#pragma unroll
          for (int cf = 0; cf < 4; ++cf) s += __expf(acc[rf][cf][j] - mx[rf][j]);
          sm[rf][j] = s;
        }
#pragma unroll
      for (int o = 1; o < 16; o <<= 1)
#pragma unroll
        for (int rf = 0; rf < 4; ++rf)
#pragma unroll
          for (int j = 0; j < 4; ++j)
            sm[rf][j] += __shfl_xor(sm[rf][j], o);
      if (ln == 0) {
#pragma unroll
        for (int rf = 0; rf < 4; ++rf)
#pragma unroll
          for (int j = 0; j < 4; ++j)
            red[rf * 16 + q * 4 + j][w] = make_float2(mx[rf][j], sm[rf][j]);
      }
    }
    LGKM_BAR();

    {  // merge 16 wave-partials: quarter q of wave w handles row w*4+q
      const int row = (w << 2) | q;
      const float2 v = red[row][ln];
      float m0v = v.x, s = v.y;
      float m = m0v;
#pragma unroll
      for (int o = 1; o < 16; o <<= 1) m = fmaxf(m, __shfl_xor(m, o));
      s *= __expf(m0v - m);
#pragma unroll
      for (int o = 1; o < 16; o <<= 1) s += __shfl_xor(s, o);
      if (ln == 0) lse_sh[row] = m + __logf(s);
    }
    LGKM_BAR();

    // ---- stores (drain during next tile's gen+GEMM) ----
    const int p = (b << 8) | (m0 + t);
    float* outb = out + (size_t)p * 65536 + w * 64 + ln;
#pragma unroll
    for (int rf = 0; rf < 4; ++rf)
#pragma unroll
      for (int j = 0; j < 4; ++j) {
        const int row = rf * 16 + q * 4 + j;
        const float lse = lse_sh[row];
        float* orow = outb + (size_t)row * 1024;
#pragma unroll
        for (int cf = 0; cf < 4; ++cf) orow[cf * 16] = acc[rf][cf][j] - lse;
      }
  }
}

extern "C" void kernel_launch(void* const* d_in, const int* in_sizes, int n_in,
                              void* d_out, int out_size, void* d_ws, size_t ws_size,
                              hipStream_t stream) {
  (void)in_sizes; (void)n_in; (void)out_size; (void)ws_size;
  const float* enc = (const float*)d_in[0];
  const float* dec = (const float*)d_in[1];
  const float* W1  = (const float*)d_in[2];
  const float* b1  = (const float*)d_in[3];
  const float* W2  = (const float*)d_in[4];
  const float* b2  = (const float*)d_in[5];
  float* out = (float*)d_out;

  char* ws = (char*)d_ws;
  unsigned short* encB = (unsigned short*)(ws + 0);        // 1 MiB   (524288 el)
  unsigned short* decB = (unsigned short*)(ws + 1048576);  // 256 KiB (131072 el)
  unsigned short* W1eB = (unsigned short*)(ws + 1310720);  // 512 KiB (262144 el)
  unsigned short* W1dB = (unsigned short*)(ws + 1835008);  // 512 KiB (262144 el)
  unsigned short* W2B  = (unsigned short*)(ws + 2359296);  // 1 MiB   (524288 el)
  float*          pe   = (float*)(ws + 3407872);           // 2 MiB  [1024][512]
  float*          pd   = (float*)(ws + 5505024);           // 512 KiB [256][512]

  prep_kernel<<<2048, 256, 0, stream>>>(enc, dec, W1, W2, encB, decB, W1eB, W1dB, W2B);
  proj_kernel<<<128, 256, 0, stream>>>(encB, W1eB, nullptr, pe);   // pe: 1024x512
  proj_kernel<<< 32, 256, 0, stream>>>(decB, W1dB, b1,      pd);   // pd:  256x512
  joint_kernel<<<256, 1024, 0, stream>>>(pe, pd, W2B, b2, out);
}

// Round 7
// 295.346 us; speedup vs baseline: 1.6925x; 1.5314x over previous
//
#include <hip/hip_runtime.h>
#include <hip/hip_bf16.h>
#include <stdint.h>

// B=4, M=256, N=64, D=512, C=1024
// out[b,m,n,c] = log_softmax_c( tanh(pe[b,m,:] + pd[b,n,:]) . W2[c,:] + b2[c] )
// pe = enc @ W1[:, :D]^T ; pd = dec @ W1[:, D:]^T + b1

typedef __bf16         bf16x8 __attribute__((ext_vector_type(8)));
typedef float          f32x4  __attribute__((ext_vector_type(4)));
typedef unsigned short u16x8  __attribute__((ext_vector_type(8)));

__device__ __forceinline__ unsigned short f2bf(float f) {
  unsigned int u = __float_as_uint(f);
  u += 0x7fffu + ((u >> 16) & 1u);          // RNE
  return (unsigned short)(u >> 16);
}

__device__ __forceinline__ f32x4 mfma16(u16x8 a, u16x8 b, f32x4 c) {
  return __builtin_amdgcn_mfma_f32_16x16x32_bf16(
      __builtin_bit_cast(bf16x8, a), __builtin_bit_cast(bf16x8, b), c, 0, 0, 0);
}

// ---------------- prep: f32 -> bf16 conversions ----------------
__global__ __launch_bounds__(256) void prep_kernel(
    const float* __restrict__ enc, const float* __restrict__ dec,
    const float* __restrict__ W1,  const float* __restrict__ W2,
    unsigned short* __restrict__ encB, unsigned short* __restrict__ decB,
    unsigned short* __restrict__ W1eB, unsigned short* __restrict__ W1dB,
    unsigned short* __restrict__ W2B)
{
  const int i = blockIdx.x * 256 + threadIdx.x;   // 0 .. 524287
  encB[i] = f2bf(enc[i]);
  W2B[i]  = f2bf(W2[i]);
  if (i < 262144) {                                // W1 is [512][1024]
    const int k = i >> 9, d = i & 511;
    W1eB[i] = f2bf(W1[k * 1024 + d]);
    W1dB[i] = f2bf(W1[k * 1024 + 512 + d]);
  }
  if (i < 131072) decB[i] = f2bf(dec[i]);
}

// ---------------- proj: out[r][c] = sum_d A[r][d]*Wt[c][d] (+bias[c]) ----------------
__global__ __launch_bounds__(256) void proj_kernel(
    const unsigned short* __restrict__ A, const unsigned short* __restrict__ Wt,
    const float* __restrict__ bias, float* __restrict__ out)
{
  const int rtile = blockIdx.x >> 3;
  const int ctile = blockIdx.x & 7;
  const int w = threadIdx.x >> 6;
  const int l = threadIdx.x & 63;
  const int q = l >> 4, ln = l & 15;

  f32x4 acc[4] = {};
  const unsigned short* Ab = A  + (size_t)(rtile * 64 + ln) * 512 + q * 8;
  const unsigned short* Wb = Wt + (size_t)(ctile * 64 + w * 16 + ln) * 512 + q * 8;

#pragma unroll 4
  for (int ks = 0; ks < 16; ++ks) {
    u16x8 bv = *(const u16x8*)(Wb + ks * 32);
#pragma unroll
    for (int rf = 0; rf < 4; ++rf) {
      u16x8 av = *(const u16x8*)(Ab + rf * 16 * 512 + ks * 32);
      acc[rf] = mfma16(av, bv, acc[rf]);
    }
  }
  const int col = ctile * 64 + w * 16 + ln;
  const float bv = bias ? bias[col] : 0.0f;
#pragma unroll
  for (int rf = 0; rf < 4; ++rf)
#pragma unroll
    for (int j = 0; j < 4; ++j)
      out[(size_t)(rtile * 64 + rf * 16 + q * 4 + j) * 512 + col] = acc[rf][j] + bv;
}

// ---------------- joint: fused tanh-GEMM + bias + log_softmax ----------------
// grid = 2*B*M = 2048 blocks, block = 512 threads (8 waves), 2 blocks/CU.
// Block bid: p = bid>>1 = (b,m); rh = bid&1 owns rows [rh*32, rh*32+32), ALL 1024 cols.
// Wave w: 32 rows x cols [w*128, w*128+128). acc[2][8] f32x4 = 64 f32/thread.
__global__ __launch_bounds__(512, 4) void joint_kernel(
    const float* __restrict__ pe, const float* __restrict__ pd,
    const unsigned short* __restrict__ W2B, const float* __restrict__ b2,
    float* __restrict__ out)
{
  __shared__ unsigned short A_sh[32 * 512];   // 32 KiB, XOR-swizzled bf16 tile
  __shared__ float2 red[32][9];               // per-row, per-wave (max, sumexp), padded
  __shared__ float  lse_sh[32];

  const int bid = blockIdx.x;
  const int p   = bid >> 1;            // b*256 + m
  const int rh  = bid & 1;             // row half
  const int b   = p >> 8;
  const int tid = threadIdx.x;
  const int w = tid >> 6, l = tid & 63;
  const int q = l >> 4, ln = l & 15;

  // ---- generate A[nl][d] = tanh(pe[m,d] + pd[rh*32+nl,d]), nl = 0..31 ----
  // wave w owns rows w*4..w*4+3; lane l owns d = l*8..l*8+7 (coalesced)
  {
    const float* per = pe + (size_t)p * 512 + l * 8;
    const float4 pe0 = *(const float4*)(per);
    const float4 pe1 = *(const float4*)(per + 4);
#pragma unroll
    for (int r = 0; r < 4; ++r) {
      const int nl = (w << 2) | r;
      const float* pdr = pd + (size_t)((b << 6) | (rh << 5) | nl) * 512 + l * 8;
      const float4 q0 = *(const float4*)(pdr);
      const float4 q1 = *(const float4*)(pdr + 4);
      float x[8] = {pe0.x + q0.x, pe0.y + q0.y, pe0.z + q0.z, pe0.w + q0.w,
                    pe1.x + q1.x, pe1.y + q1.y, pe1.z + q1.z, pe1.w + q1.w};
      u16x8 pk;
#pragma unroll
      for (int e = 0; e < 8; ++e) {
        const float ex = __expf(2.0f * x[e]);                    // tanh = 1 - 2/(e^2x+1)
        const float tv = 1.0f - 2.0f * __builtin_amdgcn_rcpf(ex + 1.0f);
        pk[e] = f2bf(tv);
      }
      *(u16x8*)((char*)A_sh + nl * 1024 + ((l ^ (nl & 7)) << 4)) = pk;
    }
  }
  __syncthreads();

  // ---- GEMM: wave w owns cols [w*128, w*128+128), rows 0..31 ----
  f32x4 acc[2][8];
#pragma unroll
  for (int rf = 0; rf < 2; ++rf)
#pragma unroll
    for (int cf = 0; cf < 8; ++cf) acc[rf][cf] = (f32x4){0.f, 0.f, 0.f, 0.f};

  const char* Abase = (const char*)A_sh + ln * 1024;   // + rf*16384, row = rf*16+ln
  const unsigned short* Wb = W2B + (size_t)(w * 128 + ln) * 512 + q * 8;  // + cf*8192 + ks*32
  const int xr = ln & 7;                                // row&7 == ln&7

  for (int ks = 0; ks < 16; ++ks) {
    u16x8 av[2];
#pragma unroll
    for (int rf = 0; rf < 2; ++rf)
      av[rf] = *(const u16x8*)(Abase + rf * 16384 + (((ks * 4 + q) ^ xr) << 4));
#pragma unroll
    for (int cfh = 0; cfh < 2; ++cfh) {
      u16x8 bv[4];
#pragma unroll
      for (int cc = 0; cc < 4; ++cc)
        bv[cc] = *(const u16x8*)(Wb + (cfh * 4 + cc) * 8192 + ks * 32);
#pragma unroll
      for (int rf = 0; rf < 2; ++rf)
#pragma unroll
        for (int cc = 0; cc < 4; ++cc)
          acc[rf][cfh * 4 + cc] = mfma16(av[rf], bv[cc], acc[rf][cfh * 4 + cc]);
    }
  }

  // ---- epilogue: + b2, log_softmax over the 1024 cols of each row ----
  float b2v[8];
#pragma unroll
  for (int cf = 0; cf < 8; ++cf) b2v[cf] = b2[w * 128 + cf * 16 + ln];
#pragma unroll
  for (int rf = 0; rf < 2; ++rf)
#pragma unroll
    for (int cf = 0; cf < 8; ++cf)
#pragma unroll
      for (int j = 0; j < 4; ++j) acc[rf][cf][j] += b2v[cf];

  // per-wave partial (max, sumexp) over this wave's 128 cols, per row
  {
    float mx[2][4], sm[2][4];
#pragma unroll
    for (int rf = 0; rf < 2; ++rf)
#pragma unroll
      for (int j = 0; j < 4; ++j) {
        float m = acc[rf][0][j];
#pragma unroll
        for (int cf = 1; cf < 8; ++cf) m = fmaxf(m, acc[rf][cf][j]);
        mx[rf][j] = m;
      }
#pragma unroll
    for (int o = 1; o < 16; o <<= 1)
#pragma unroll
      for (int rf = 0; rf < 2; ++rf)
#pragma unroll
        for (int j = 0; j < 4; ++j)
          mx[rf][j] = fmaxf(mx[rf][j], __shfl_xor(mx[rf][j], o));
#pragma unroll
    for (int rf = 0; rf < 2; ++rf)
#pragma unroll
      for (int j = 0; j < 4; ++j) {
        float s = 0.f;
#pragma unroll
        for (int cf = 0; cf < 8; ++cf) s += __expf(acc[rf][cf][j] - mx[rf][j]);
        sm[rf][j] = s;
      }
#pragma unroll
    for (int o = 1; o < 16; o <<= 1)
#pragma unroll
      for (int rf = 0; rf < 2; ++rf)
#pragma unroll
        for (int j = 0; j < 4; ++j)
          sm[rf][j] += __shfl_xor(sm[rf][j], o);
    if (ln == 0) {
#pragma unroll
      for (int rf = 0; rf < 2; ++rf)
#pragma unroll
        for (int j = 0; j < 4; ++j)
          red[rf * 16 + q * 4 + j][w] = make_float2(mx[rf][j], sm[rf][j]);
    }
  }
  __syncthreads();

  // merge the 8 wave-partials: thread tid<32 handles row tid
  if (tid < 32) {
    float m = red[tid][0].x;
#pragma unroll
    for (int ww = 1; ww < 8; ++ww) m = fmaxf(m, red[tid][ww].x);
    float s = 0.f;
#pragma unroll
    for (int ww = 0; ww < 8; ++ww) s += red[tid][ww].y * __expf(red[tid][ww].x - m);
    lse_sh[tid] = m + __logf(s);
  }
  __syncthreads();

  // final: out = acc - lse  (nontemporal: never re-read; keep L2 for W2)
  float* outb = out + (size_t)p * 65536 + (rh << 5) * 1024 + w * 128 + ln;
#pragma unroll
  for (int rf = 0; rf < 2; ++rf)
#pragma unroll
    for (int j = 0; j < 4; ++j) {
      const int row = rf * 16 + q * 4 + j;
      const float lse = lse_sh[row];
      float* orow = outb + (size_t)row * 1024;
#pragma unroll
      for (int cf = 0; cf < 8; ++cf)
        __builtin_nontemporal_store(acc[rf][cf][j] - lse, orow + cf * 16);
    }
}

extern "C" void kernel_launch(void* const* d_in, const int* in_sizes, int n_in,
                              void* d_out, int out_size, void* d_ws, size_t ws_size,
                              hipStream_t stream) {
  (void)in_sizes; (void)n_in; (void)out_size; (void)ws_size;
  const float* enc = (const float*)d_in[0];
  const float* dec = (const float*)d_in[1];
  const float* W1  = (const float*)d_in[2];
  const float* b1  = (const float*)d_in[3];
  const float* W2  = (const float*)d_in[4];
  const float* b2  = (const float*)d_in[5];
  float* out = (float*)d_out;

  char* ws = (char*)d_ws;
  unsigned short* encB = (unsigned short*)(ws + 0);        // 1 MiB   (524288 el)
  unsigned short* decB = (unsigned short*)(ws + 1048576);  // 256 KiB (131072 el)
  unsigned short* W1eB = (unsigned short*)(ws + 1310720);  // 512 KiB (262144 el)
  unsigned short* W1dB = (unsigned short*)(ws + 1835008);  // 512 KiB (262144 el)
  unsigned short* W2B  = (unsigned short*)(ws + 2359296);  // 1 MiB   (524288 el)
  float*          pe   = (float*)(ws + 3407872);           // 2 MiB  [1024][512]
  float*          pd   = (float*)(ws + 5505024);           // 512 KiB [256][512]

  prep_kernel<<<2048, 256, 0, stream>>>(enc, dec, W1, W2, encB, decB, W1eB, W1dB, W2B);
  proj_kernel<<<128, 256, 0, stream>>>(encB, W1eB, nullptr, pe);   // pe: 1024x512
  proj_kernel<<< 32, 256, 0, stream>>>(decB, W1dB, b1,      pd);   // pd:  256x512
  joint_kernel<<<2048, 512, 0, stream>>>(pe, pd, W2B, b2, out);
}